// Round 1
// 55.187 us; speedup vs baseline: 1.5872x; 1.5872x over previous
//
#include <hip/hip_runtime.h>

// Problem: B=32, NC=4, H=512, W=512, fp32 in, two fp32 scalars out.
// lseg = mean BCE-with-logits; liou = 1 - mean_b( sum_c IoU(b,c) / present(b) ).
//
// R3 post-mortem: VGPR=56 -> double buffer collapsed AGAIN (needs 64 payload
// regs). Occupancy 34% with a 1024-block grid (hard cap 50%: 16/32 waves/CU).
// R4 theory: stop fighting the allocator for ILP; buy TLP instead.
//   - grid 1024 -> 2048 blocks (8 blocks/CU * 4 waves = 32 waves/CU = 100%),
//     __launch_bounds__(256,8) caps VGPR at 64 so full occupancy is legal.
//   - single load batch per iter (8x float4 = 32 regs), no sched games.
//   - 8-bit packed counter accumulation (counts <= 16/thread at ITERS=4).
//   - block-level LDS reduction: 13 atomics/block not /wave; BCE goes to
//     per-batch slots to kill single-address atomic contention.

#define NB   32
#define NCL  4
constexpr int HW      = 512 * 512;       // 262144 pixels per (b,c) plane
constexpr int GROUPS  = HW / 4;          // 65536 float4-groups per plane
constexpr int THREADS = 256;
constexpr int BLOCKS_PER_BATCH = 64;
constexpr int TPB = BLOCKS_PER_BATCH * THREADS;   // 16384 threads per batch
constexpr int ITERS = GROUPS / TPB;               // 4 groups (16 pixels)/thread

__global__ __launch_bounds__(THREADS, 8)   // force <=64 VGPR: 8 waves/SIMD
void seg_main(const float* __restrict__ pred,
              const float* __restrict__ tgt,
              float* __restrict__ bce_part,  // [NB] per-batch BCE partials
              unsigned* __restrict__ pc_g,   // [NB][NCL] pred counts
              unsigned* __restrict__ tc_g,   // [NB][NCL] tgt counts
              unsigned* __restrict__ tp_g)   // [NB][NCL] true positives
{
    const int b     = blockIdx.x & (NB - 1);       // one batch per block
    const int chunk = blockIdx.x >> 5;             // 0..BLOCKS_PER_BATCH-1
    const int tib   = chunk * THREADS + threadIdx.x;

    const float* pp[NCL];
    const float* tq[NCL];
    {
        const size_t t0 = (size_t)b * NCL * HW + 4u * (size_t)tib;
#pragma unroll
        for (int c = 0; c < NCL; ++c) {
            pp[c] = pred + t0 + (size_t)c * HW;
            tq[c] = tgt  + t0 + (size_t)c * HW;
        }
    }

    float bce = 0.0f;
    // 8-bit fields: per-thread per-class count <= ITERS*4 = 16 < 255
    unsigned pcP = 0u, tcP = 0u, tpP = 0u;

#pragma unroll
    for (int it = 0; it < ITERS; ++it) {
        const size_t soff = (size_t)it * 4u * TPB;
        float4 pv[NCL], tv[NCL];
#pragma unroll
        for (int c = 0; c < NCL; ++c) {
            pv[c] = *reinterpret_cast<const float4*>(pp[c] + soff);
            tv[c] = *reinterpret_cast<const float4*>(tq[c] + soff);
        }
#pragma unroll
        for (int j = 0; j < 4; ++j) {
            float pj[NCL], tj[NCL];
#pragma unroll
            for (int c = 0; c < NCL; ++c) {
                pj[c] = (&pv[c].x)[j];
                tj[c] = (&tv[c].x)[j];
            }
            // first-occurrence argmax (strict >) matches jnp.argmax
            int cp = 0, ct = 0;
            float bp = pj[0], bt = tj[0];
#pragma unroll
            for (int c = 1; c < NCL; ++c) {
                if (pj[c] > bp) { bp = pj[c]; cp = c; }
                if (tj[c] > bt) { bt = tj[c]; ct = c; }
            }
            const unsigned op = 1u << (cp << 3);
            const unsigned ot = 1u << (ct << 3);
            pcP += op;
            tcP += ot;
            tpP += (cp == ct) ? op : 0u;
            // BCE with logits, numerically stable
#pragma unroll
            for (int c = 0; c < NCL; ++c) {
                const float p = pj[c];
                bce += fmaxf(p, 0.0f) - p * tj[c]
                     + __logf(1.0f + __expf(-fabsf(p)));
            }
        }
    }

    // unpack 8-bit fields, repack as 16-bit fields in u64 for the wave
    // reduction (64-lane sum <= 16*64 = 1024 < 65536, no overflow)
    unsigned long long P = 0ull, T = 0ull, Q = 0ull;
#pragma unroll
    for (int c = 0; c < NCL; ++c) {
        P |= (unsigned long long)((pcP >> (8 * c)) & 0xFFu) << (16 * c);
        T |= (unsigned long long)((tcP >> (8 * c)) & 0xFFu) << (16 * c);
        Q |= (unsigned long long)((tpP >> (8 * c)) & 0xFFu) << (16 * c);
    }
#pragma unroll
    for (int o = 32; o > 0; o >>= 1) {
        bce += __shfl_xor(bce, o);
        P   += __shfl_xor(P, o);
        T   += __shfl_xor(T, o);
        Q   += __shfl_xor(Q, o);
    }

    // block-level reduction: 4 waves -> one set of atomics per block.
    // block sum per field <= 4*1024 = 4096 < 65536: still no overflow.
    __shared__ float              s_bce[THREADS / 64];
    __shared__ unsigned long long sP[THREADS / 64];
    __shared__ unsigned long long sT[THREADS / 64];
    __shared__ unsigned long long sQ[THREADS / 64];
    const int wid = threadIdx.x >> 6;
    if ((threadIdx.x & 63) == 0) {
        s_bce[wid] = bce; sP[wid] = P; sT[wid] = T; sQ[wid] = Q;
    }
    __syncthreads();
    if (threadIdx.x == 0) {
        float bs = s_bce[0] + s_bce[1] + s_bce[2] + s_bce[3];
        unsigned long long Ps = sP[0] + sP[1] + sP[2] + sP[3];
        unsigned long long Ts = sT[0] + sT[1] + sT[2] + sT[3];
        unsigned long long Qs = sQ[0] + sQ[1] + sQ[2] + sQ[3];
        atomicAdd(&bce_part[b], bs);
#pragma unroll
        for (int c = 0; c < NCL; ++c) {
            atomicAdd(&pc_g[b * NCL + c], (unsigned)((Ps >> (16 * c)) & 0xFFFFu));
            atomicAdd(&tc_g[b * NCL + c], (unsigned)((Ts >> (16 * c)) & 0xFFFFu));
            atomicAdd(&tp_g[b * NCL + c], (unsigned)((Qs >> (16 * c)) & 0xFFFFu));
        }
    }
}

__global__ void seg_final(const float* __restrict__ bce_part,
                          const unsigned* __restrict__ pc_g,
                          const unsigned* __restrict__ tc_g,
                          const unsigned* __restrict__ tp_g,
                          float* __restrict__ out)
{
    const int t = threadIdx.x;
    float val = 0.0f;
    float bs  = 0.0f;
    if (t < NB) {
        bs = bce_part[t];
        float iou = 0.0f;
        int present = 0;
#pragma unroll
        for (int c = 0; c < NCL; ++c) {
            const float P = (float)pc_g[t * NCL + c];
            const float T = (float)tc_g[t * NCL + c];
            const float K = (float)tp_g[t * NCL + c];
            const float den = P + T - K;
            if (den > 0.0f) iou += K / den;
            present += (tc_g[t * NCL + c] > 0u);
        }
        val = iou / (float)present;   // present >= 1 always (sum_c tgt_cnt = HW)
    }
#pragma unroll
    for (int o = 32; o > 0; o >>= 1) {
        val += __shfl_xor(val, o);
        bs  += __shfl_xor(bs, o);
    }
    if (t == 0) {
        out[0] = bs / (float)((size_t)NB * NCL * HW);  // lseg
        out[1] = 1.0f - val / (float)NB;               // liou
    }
}

extern "C" void kernel_launch(void* const* d_in, const int* in_sizes, int n_in,
                              void* d_out, int out_size, void* d_ws, size_t ws_size,
                              hipStream_t stream) {
    const float* pred = (const float*)d_in[0];
    const float* tgt  = (const float*)d_in[1];
    float* out = (float*)d_out;

    // workspace layout: [0,128): bce_part[32]; [256,...): 3 x 128 uint counters
    float*    bce_part = (float*)d_ws;
    unsigned* pc_g     = (unsigned*)((char*)d_ws + 256);
    unsigned* tc_g     = pc_g + NB * NCL;
    unsigned* tp_g     = tc_g + NB * NCL;

    hipMemsetAsync(d_ws, 0, 256 + 3 * NB * NCL * sizeof(unsigned), stream);
    seg_main<<<NB * BLOCKS_PER_BATCH, THREADS, 0, stream>>>(pred, tgt, bce_part,
                                                            pc_g, tc_g, tp_g);
    seg_final<<<1, 64, 0, stream>>>(bce_part, pc_g, tc_g, tp_g, out);
}